// Round 6
// baseline (246.009 us; speedup 1.0000x reference)
//
#include <hip/hip_runtime.h>
#include <hip/hip_bf16.h>
#include <stdint.h>

// Problem: B=32, C_IN=128, H=W=64, K=8, C_OUT=128, KS=3, HID=512, pad=1
// Pipeline (Round-6):
//  0) prompt_pre:   pp_part[k][js] = prompt[k] @ w2[js-chunk] (j-split x8)
//  1) pool_convert: x fp32 NCHW -> per-(b,h) partial sums + xT bf16 NHWC
//  2) attn_fused:   partial -> pooled -> h -> scores(pp_part) -> softmax
//  3) agg_weights:  alphas x kernels_weights -> aggw bf16 [b][tap][co][ci]
//  4) dyn_conv:     implicit-GEMM conv, Round-6: back to M=128 x N=128 tile
//     (VGPR ~124), FULL unroll (R3's VALU win), but A staged per SUB-CHUNK
//     (2x8KB dbuf) -> LDS 50.7KB -> 3 blocks/CU (occupancy is the proven
//     dominant lever; R5's 1-block/CU config regressed). XCD-aware tile
//     swizzle: 4 consecutive 2-row tiles per XCD -> halo rows L2-shared
//     (R5 measured FETCH 69->61MB from halo sharing; swizzle gets it free).

typedef __bf16 v8bf __attribute__((ext_vector_type(8)));
typedef float  v4f  __attribute__((ext_vector_type(4)));

// ---- workspace layout (bytes) ----
#define XT_OFF     0u
#define XT_BYTES   (32u*4096u*128u*2u)        // 33,554,432  x as bf16 NHWC
#define AGGW_OFF   (XT_OFF + XT_BYTES)
#define AGGW_BYTES (32u*9u*128u*128u*2u)      // 9,437,184   [b][tap][co][ci]
// scratch below ALIASES the AGGW region: all consumed before agg_weights writes
#define PART_OFF   (AGGW_OFF)                 // 32*64*128 fp32 = 1 MB
#define PP_OFF     (AGGW_OFF + 0x100000u)     // 8*8*512 fp32 = 128 KB
#define PBP_OFF    (AGGW_OFF + 0x120000u)     // 64 fp32
#define ALPHA_OFF  (AGGW_OFF + AGGW_BYTES)
#define ALPHA_BYTES (32u*8u*4u)
#define AGGB_OFF   (ALPHA_OFF + ALPHA_BYTES)
#define AGGB_BYTES (32u*128u*4u)

typedef const void __attribute__((address_space(1))) gconst_t;
typedef void       __attribute__((address_space(3))) ldsv_t;

__device__ __forceinline__ void g2l16(const void* g, void* l) {
  // async global->LDS, 16B/lane; LDS dest is wave-uniform base (HW adds lane*16)
  __builtin_amdgcn_global_load_lds((gconst_t*)g, (ldsv_t*)l, 16, 0, 0);
}

// ---------------- Kernel 0: prompt premix, j-split x8 ------------------------
// grid = (8 k, 8 js), 512 threads (i). 64-deep reduction -> latency-cheap.
__global__ __launch_bounds__(512) void prompt_pre_kernel(
    const float* __restrict__ prompt, const float* __restrict__ w2,
    const float* __restrict__ b2, float* __restrict__ pp,
    float* __restrict__ pbp) {
  const int k = blockIdx.x, js = blockIdx.y;
  const int i = threadIdx.x;
  __shared__ float sP[64];
  if (i < 64) sP[i] = prompt[k * 512 + js * 64 + i];
  __syncthreads();
  float acc = 0.0f;
  const float* wcol = w2 + (js * 64) * 512 + i;   // coalesced over i
  #pragma unroll 8
  for (int jj = 0; jj < 64; ++jj) acc = fmaf(sP[jj], wcol[jj * 512], acc);
  pp[(k * 8 + js) * 512 + i] = acc;
  if (i < 64) {                                   // pb partial via wave-0 reduce
    float v = sP[i] * b2[js * 64 + i];
    #pragma unroll
    for (int m = 32; m > 0; m >>= 1) v += __shfl_xor(v, m);
    if (i == 0) pbp[k * 8 + js] = v;
  }
}

// ---------------- Kernel 1: pooling partials + NCHW->NHWC bf16 ---------------
// grid = B*H = 2048 blocks, 256 threads. Each block handles one (b,h) row slab.
__global__ __launch_bounds__(256) void pool_convert_kernel(
    const float* __restrict__ x, float* __restrict__ partial,
    __hip_bfloat16* __restrict__ xT) {
  const int b = blockIdx.x >> 6;
  const int h = blockIdx.x & 63;
  const int tid = threadIdx.x;
  const int wv = tid >> 6, lane = tid & 63;
  const int wq = lane & 15;                    // w-quad (4 w's) within row
  const int cl = lane >> 4;                    // channel within group-of-4
  // [w][c] transpose buffer; pitch 130 elems (260B) => 2-way bank aliasing (free)
  __shared__ __align__(16) __hip_bfloat16 sT[64 * 130];

  const float* xrow = x + (((size_t)b * 128) << 12) + (h << 6);
  #pragma unroll
  for (int i = 0; i < 8; ++i) {
    int c = wv * 32 + i * 4 + cl;              // each wave: 32 channels
    float4 v = *(const float4*)&xrow[((size_t)c << 12) + wq * 4];
    int w0 = wq * 4;
    sT[(w0 + 0) * 130 + c] = __float2bfloat16(v.x);
    sT[(w0 + 1) * 130 + c] = __float2bfloat16(v.y);
    sT[(w0 + 2) * 130 + c] = __float2bfloat16(v.z);
    sT[(w0 + 3) * 130 + c] = __float2bfloat16(v.w);
    float s = v.x + v.y + v.z + v.w;
    s += __shfl_xor(s, 1);
    s += __shfl_xor(s, 2);
    s += __shfl_xor(s, 4);
    s += __shfl_xor(s, 8);                     // sum over the 16-lane group
    if (wq == 0) partial[((b << 6) + h) * 128 + c] = s;  // unique slot
  }
  __syncthreads();
  // write NHWC: position (h,pw) has 256B of ci; 4 threads/position, 64B each
  const int pw = tid >> 2;
  const int piece = tid & 3;
  const uint32_t* s32 = (const uint32_t*)sT;
  uint32_t vals[16];
  #pragma unroll
  for (int j = 0; j < 16; ++j) vals[j] = s32[pw * 65 + piece * 16 + j];
  char* dst = (char*)xT + ((((size_t)b << 6) + h) * 64 + pw) * 256 + piece * 64;
  #pragma unroll
  for (int j = 0; j < 4; ++j)
    ((uint4*)dst)[j] = make_uint4(vals[4*j], vals[4*j+1], vals[4*j+2], vals[4*j+3]);
}

// ---------------- Kernel 2: fused attention ----------------------------------
// grid = 32 (b), 256 threads.
__global__ __launch_bounds__(256) void attn_fused_kernel(
    const float* __restrict__ partial, const float* __restrict__ w1,
    const float* __restrict__ b1, const float* __restrict__ pp,
    const float* __restrict__ pbp, const float* __restrict__ kbias,
    float* __restrict__ alphas, float* __restrict__ aggb) {
  const int b = blockIdx.x, tid = threadIdx.x;
  __shared__ float sTmp[256];
  __shared__ float sPool[128];
  __shared__ float sH[512];
  __shared__ float sS[8], sA[8];

  {  // 1) reduce partial[b][64][128] -> pooled. c = tid&127 (coalesced), 2 h-lanes
    const int c = tid & 127, hh = tid >> 7;
    const float* src = partial + ((size_t)b << 6) * 128 + hh * 128 + c;
    float acc = 0.0f;
    #pragma unroll
    for (int h2 = 0; h2 < 32; ++h2) acc += src[h2 * 256];
    sTmp[tid] = acc;
  }
  __syncthreads();
  if (tid < 128) sPool[tid] = (sTmp[tid] + sTmp[tid + 128]) * (1.0f / 4096.0f);
  __syncthreads();

  // 2) h = relu(pooled @ w1^T + b1): each thread 2 rows of w1 (L2-shared)
  #pragma unroll
  for (int q = 0; q < 2; ++q) {
    const int j = q * 256 + tid;
    const float* wr = w1 + j * 128;
    float acc = 0.0f;
    #pragma unroll
    for (int i4 = 0; i4 < 32; ++i4) {
      float4 wv = *(const float4*)&wr[i4 * 4];
      acc += wv.x * sPool[i4*4] + wv.y * sPool[i4*4+1] +
             wv.z * sPool[i4*4+2] + wv.w * sPool[i4*4+3];
    }
    sH[j] = fmaxf(acc + b1[j], 0.0f);
  }
  __syncthreads();

  {  // 3) scores[k] = sum_js pp_part[k][js]·h + sum_js pbp[k][js]
    const int k = tid >> 5, seg = tid & 31;
    const float* hk = sH + seg * 16;
    float acc = 0.0f;
    #pragma unroll
    for (int js = 0; js < 8; ++js) {
      const float* ppk = pp + (k * 8 + js) * 512 + seg * 16;
      #pragma unroll
      for (int t4 = 0; t4 < 4; ++t4) {
        float4 pv = *(const float4*)&ppk[t4 * 4];
        acc += pv.x * hk[t4*4] + pv.y * hk[t4*4+1] +
               pv.z * hk[t4*4+2] + pv.w * hk[t4*4+3];
      }
    }
    #pragma unroll
    for (int m = 16; m > 0; m >>= 1) acc += __shfl_xor(acc, m);
    if (seg == 0) {
      float pbk = 0.0f;
      #pragma unroll
      for (int js = 0; js < 8; ++js) pbk += pbp[k * 8 + js];
      sS[k] = acc + pbk;
    }
  }
  __syncthreads();

  // 4) softmax + outputs
  if (tid == 0) {
    float mx = sS[0];
    for (int k = 1; k < 8; ++k) mx = fmaxf(mx, sS[k]);
    float sum = 0.0f, e[8];
    for (int k = 0; k < 8; ++k) { e[k] = expf(sS[k] - mx); sum += e[k]; }
    float inv = 1.0f / sum;
    for (int k = 0; k < 8; ++k) sA[k] = e[k] * inv;
  }
  __syncthreads();
  if (tid < 8) alphas[b * 8 + tid] = sA[tid];
  if (tid < 128) {
    float acc = 0.0f;
    #pragma unroll
    for (int k = 0; k < 8; ++k) acc = fmaf(sA[k], kbias[k * 128 + tid], acc);
    aggb[b * 128 + tid] = acc;
  }
}

// ---------------- Kernel 3: aggregate conv weights -> bf16 -------------------
// grid = (co=128, bgroup=4), 128 threads.
__global__ __launch_bounds__(128) void agg_weights_kernel(
    const float* __restrict__ kw, const float* __restrict__ alphas,
    __hip_bfloat16* __restrict__ aggw) {
  const int co = blockIdx.x;
  const int bg = blockIdx.y;
  const int tid = threadIdx.x;
  __shared__ float sA[64];                          // [bb][k]
  __shared__ float sbuf[1152];
  if (tid < 64) sA[tid] = alphas[bg * 64 + tid];
  __syncthreads();

  float acc[8][9];                                  // [bb][q], f = tid + 128*q
  #pragma unroll
  for (int bb = 0; bb < 8; ++bb)
    #pragma unroll
    for (int q = 0; q < 9; ++q) acc[bb][q] = 0.0f;

  for (int k = 0; k < 8; ++k) {
    const float* src = kw + ((size_t)(k * 128 + co)) * 1152;
    float v[9];
    #pragma unroll
    for (int q = 0; q < 9; ++q) v[q] = src[tid + 128 * q];   // coalesced
    #pragma unroll
    for (int bb = 0; bb < 8; ++bb) {
      float a = sA[bb * 8 + k];
      #pragma unroll
      for (int q = 0; q < 9; ++q) acc[bb][q] = fmaf(a, v[q], acc[bb][q]);
    }
  }

  #pragma unroll 1
  for (int bb = 0; bb < 8; ++bb) {
    __syncthreads();
    #pragma unroll
    for (int q = 0; q < 9; ++q) sbuf[tid + 128 * q] = acc[bb][q];
    __syncthreads();
    const int b = bg * 8 + bb;
    // sbuf[f] with f = ci*9 + t; lanes read stride 9 (9 coprime 32: conflict-free)
    #pragma unroll
    for (int t = 0; t < 9; ++t)
      aggw[(((size_t)(b * 9 + t) * 128 + co) << 7) + tid] =
          __float2bfloat16(sbuf[tid * 9 + t]);     // 256B contiguous store
  }
}

// ---------------- Kernel 4: per-sample conv as implicit GEMM -----------------
// Round-6. Block tile: M=128 (co) x N=128 (2 rows x 64 cols), acc[4][4]/wave.
// K-loop: 2 halves x 18 chunks (9 taps x 2 subs) of BK=32, 16x16x32 bf16 MFMA.
// x staged per ci-half in LDS NHWC with 16B XOR swizzle; A staged per
// SUB-CHUNK in 2x8KB dbuf (stage c+2 after barrier; R0-proven pattern).
// LDS = 50.7KB -> 3 blocks/CU; full unroll -> no runtime division.
// XCD swizzle: tile=(x&7)*4+(x>>3) puts 4 consecutive tiles on one XCD
// (linear id % 8 = x % 8 since gridDim.x=32) -> halo rows L2-shared.
#define XTILE_B 33792   // 264 positions * 128B (64 ci bf16)
#define ABUF_B  8192    // one sub-chunk: 128 co * 64B

__global__ __launch_bounds__(256, 3) void dyn_conv_kernel(
    const __hip_bfloat16* __restrict__ xT, const __hip_bfloat16* __restrict__ aggw,
    const float* __restrict__ aggb, float* __restrict__ out) {
  // XCD-aware tile swizzle (bijective on 0..31)
  const int tile = ((blockIdx.x & 7) << 2) | (blockIdx.x >> 3);
  const int b    = blockIdx.y;   // sample
  const int tid  = threadIdx.x;
  const int wv = tid >> 6, lane = tid & 63;
  const int wm = wv >> 1, wn = wv & 1;
  const int lm = lane & 15, quad = lane >> 4;
  const int r0 = tile * 2;

  __shared__ __align__(16) char smem[XTILE_B + 2 * ABUF_B + 512];
  char* xb = smem;
  char* abuf = smem + XTILE_B;
  float* sBias = (float*)(smem + XTILE_B + 2 * ABUF_B);

  if (tid < 128) sBias[tid] = aggb[b * 128 + tid];

  // zero-fill halo slots that staging never writes (pad cols / out-of-range rows)
  for (int pos = tid; pos < 264; pos += 256) {
    int tr = pos / 66, tc = pos - tr * 66;
    int h = r0 - 1 + tr, w = tc - 1;
    if ((unsigned)h >= 64u || (unsigned)w >= 64u) {
      int4* d = (int4*)(xb + pos * 128);
      #pragma unroll
      for (int i = 0; i < 8; ++i) d[i] = make_int4(0, 0, 0, 0);
    }
  }

  const char* xTb = (const char*)xT + ((size_t)b << 20);     // b*4096*256
  const char* awb = (const char*)aggw + (size_t)b * 294912;  // b*9*128*256

  auto stageX = [&](int half) {
    for (int i = wv; i < 33; i += 4) {          // 33 issues of 64x16B = 1KB
      int P = (i << 6) + lane;
      int pos = P >> 3, slot = P & 7;
      int tr = pos / 66, tc = pos - tr * 66;
      int h = r0 - 1 + tr, w = tc - 1;
      char* dst = xb + (i << 10);               // wave-uniform LDS base
      if ((unsigned)h < 64u && (unsigned)w < 64u) {
        int p = slot ^ (pos & 7);               // swizzled source piece
        const char* src = xTb + (((h << 6) + w) << 8) + (half << 7) + (p << 4);
        g2l16(src, dst);
      }
    }
  };

  // stage one sub-chunk (8KB) into buffer c&1: 2 g2l16 per wave, branch-free
  auto stageA = [&](int c, int half) {          // c = chunk 0..17 within half
    const int tap = c >> 1, sub = c & 1;
    const int cic = half * 2 + sub;             // ci chunk 0..3
    char* ab = abuf + (c & 1) * ABUF_B;
    const char* base = awb + (tap << 15) + (cic << 6);
    #pragma unroll
    for (int jj = 0; jj < 2; ++jj) {
      int j = wv * 2 + jj;
      int co = (j << 4) + (lane >> 2);
      int f = lane & 3;
      int p = f ^ ((co >> 1) & 3);              // swizzled source piece
      g2l16(base + (co << 8) + (p << 4), ab + (j << 10));
    }
  };

  int posb[4];
  #pragma unroll
  for (int ni = 0; ni < 4; ++ni) {
    int n = wn * 64 + ni * 16 + lm;
    posb[ni] = (n >> 6) * 66 + (n & 63);
  }
  const int fA = (quad ^ ((lm >> 1) & 3)) << 4;
  int aoff[4];
  #pragma unroll
  for (int mi = 0; mi < 4; ++mi) {
    int co = wm * 64 + mi * 16 + lm;
    aoff[mi] = (co << 6) + fA;
  }

  v4f acc[4][4];
  #pragma unroll
  for (int mi = 0; mi < 4; ++mi)
    #pragma unroll
    for (int ni = 0; ni < 4; ++ni) acc[mi][ni] = v4f{0.f, 0.f, 0.f, 0.f};

  auto computeChunk = [&](int c) {              // c compile-time under unroll
    const int tap = c >> 1, sub = c & 1;
    const int th = tap / 3, tw = tap - th * 3;
    const int tapAdd = th * 66 + tw;
    char* ab = abuf + (c & 1) * ABUF_B;
    v8bf af[4], bfr[4];
    #pragma unroll
    for (int mi = 0; mi < 4; ++mi) af[mi] = *(const v8bf*)(ab + aoff[mi]);
    const int piece = (sub << 2) | quad;        // ci piece within half
    #pragma unroll
    for (int ni = 0; ni < 4; ++ni) {
      int pos = posb[ni] + tapAdd;
      int pq = (piece ^ (pos & 7)) << 4;
      bfr[ni] = *(const v8bf*)(xb + (pos << 7) + pq);
    }
    #pragma unroll
    for (int mi = 0; mi < 4; ++mi)
      #pragma unroll
      for (int ni = 0; ni < 4; ++ni)
        acc[mi][ni] = __builtin_amdgcn_mfma_f32_16x16x32_bf16(
            af[mi], bfr[ni], acc[mi][ni], 0, 0, 0);
  };

  // ---- half 0 ----
  stageA(0, 0);
  stageA(1, 0);
  stageX(0);
  __syncthreads();                              // drains all staging
  #pragma unroll
  for (int c = 0; c < 18; ++c) {
    computeChunk(c);
    __syncthreads();                            // all waves done with buf c&1
    if (c + 2 < 18) stageA(c + 2, 0);           // lands during computeChunk(c+1)
  }
  // ---- half transition (all buffers free after chunk-17 barrier) ----
  stageX(1);
  stageA(0, 1);
  stageA(1, 1);
  __syncthreads();
  // ---- half 1 ----
  #pragma unroll
  for (int c = 0; c < 18; ++c) {
    computeChunk(c);
    if (c < 17) {
      __syncthreads();
      if (c + 2 < 18) stageA(c + 2, 1);
    }
  }

  // ---- epilogue: C/D layout col=lane&15, row=quad*4+reg ----
  #pragma unroll
  for (int mi = 0; mi < 4; ++mi) {
    #pragma unroll
    for (int r = 0; r < 4; ++r) {
      int co = wm * 64 + mi * 16 + quad * 4 + r;
      float bias = sBias[co];
      #pragma unroll
      for (int ni = 0; ni < 4; ++ni) {
        int n = wn * 64 + ni * 16 + lm;
        out[(((size_t)(b * 128 + co)) << 12) + tile * 128 + n] =
            acc[mi][ni][r] + bias;
      }
    }
  }
}

// ---------------------------------- launch -----------------------------------
extern "C" void kernel_launch(void* const* d_in, const int* in_sizes, int n_in,
                              void* d_out, int out_size, void* d_ws, size_t ws_size,
                              hipStream_t stream) {
  const float* x      = (const float*)d_in[0];
  const float* prompt = (const float*)d_in[1];
  const float* w1     = (const float*)d_in[2];
  const float* b1     = (const float*)d_in[3];
  const float* w2     = (const float*)d_in[4];
  const float* b2     = (const float*)d_in[5];
  const float* kw     = (const float*)d_in[6];
  const float* kb     = (const float*)d_in[7];
  float* out = (float*)d_out;
  char* ws = (char*)d_ws;

  __hip_bfloat16* xT   = (__hip_bfloat16*)(ws + XT_OFF);
  __hip_bfloat16* aggw = (__hip_bfloat16*)(ws + AGGW_OFF);
  float* part   = (float*)(ws + PART_OFF);     // aliases AGGW (dead before agg)
  float* pp     = (float*)(ws + PP_OFF);       // "
  float* pbp    = (float*)(ws + PBP_OFF);      // "
  float* alphas = (float*)(ws + ALPHA_OFF);
  float* aggb   = (float*)(ws + AGGB_OFF);

  prompt_pre_kernel<<<dim3(8, 8), 512, 0, stream>>>(prompt, w2, b2, pp, pbp);
  pool_convert_kernel<<<2048, 256, 0, stream>>>(x, part, xT);
  attn_fused_kernel<<<32, 256, 0, stream>>>(part, w1, b1, pp, pbp, kb,
                                            alphas, aggb);
  agg_weights_kernel<<<dim3(128, 4), 128, 0, stream>>>(kw, alphas, aggw);
  dyn_conv_kernel<<<dim3(32, 32), 256, 0, stream>>>(xT, aggw, aggb, out);
}

// Round 7
// 214.380 us; speedup vs baseline: 1.1475x; 1.1475x over previous
//
#include <hip/hip_runtime.h>
#include <hip/hip_bf16.h>
#include <stdint.h>

// Problem: B=32, C_IN=128, H=W=64, K=8, C_OUT=128, KS=3, HID=512, pad=1
// Pipeline (Round-7):
//  0) prompt_pre:   pp_part[k][js] = prompt[k] @ w2[js-chunk] (j-split x8)
//  1) pool_convert: x fp32 NCHW -> per-(b,h) partial sums + xT bf16 NHWC
//  2) attn_fused:   partial -> pooled -> h -> scores(pp_part) -> softmax
//  3) agg_weights:  alphas x kernels_weights -> aggw bf16 [b][tap][co][ci]
//  4) dyn_conv:     implicit-GEMM conv. Round-7 = Round-6 with the two
//     contaminants removed: NO forced min-occupancy (R6's launch_bounds(256,3)
//     collapsed VGPR 124->84 and spilled: WRITE_SIZE 65.5->130MB) and NO XCD
//     swizzle. Sub-chunk A staging (2x8KB dbuf) -> LDS 50.7KB -> 3 blocks/CU
//     at natural ~124 VGPR; full unroll (R3's proven VALU win).

typedef __bf16 v8bf __attribute__((ext_vector_type(8)));
typedef float  v4f  __attribute__((ext_vector_type(4)));

// ---- workspace layout (bytes) ----
#define XT_OFF     0u
#define XT_BYTES   (32u*4096u*128u*2u)        // 33,554,432  x as bf16 NHWC
#define AGGW_OFF   (XT_OFF + XT_BYTES)
#define AGGW_BYTES (32u*9u*128u*128u*2u)      // 9,437,184   [b][tap][co][ci]
// scratch below ALIASES the AGGW region: all consumed before agg_weights writes
#define PART_OFF   (AGGW_OFF)                 // 32*64*128 fp32 = 1 MB
#define PP_OFF     (AGGW_OFF + 0x100000u)     // 8*8*512 fp32 = 128 KB
#define PBP_OFF    (AGGW_OFF + 0x120000u)     // 64 fp32
#define ALPHA_OFF  (AGGW_OFF + AGGW_BYTES)
#define ALPHA_BYTES (32u*8u*4u)
#define AGGB_OFF   (ALPHA_OFF + ALPHA_BYTES)
#define AGGB_BYTES (32u*128u*4u)

typedef const void __attribute__((address_space(1))) gconst_t;
typedef void       __attribute__((address_space(3))) ldsv_t;

__device__ __forceinline__ void g2l16(const void* g, void* l) {
  // async global->LDS, 16B/lane; LDS dest is wave-uniform base (HW adds lane*16)
  __builtin_amdgcn_global_load_lds((gconst_t*)g, (ldsv_t*)l, 16, 0, 0);
}

// ---------------- Kernel 0: prompt premix, j-split x8 ------------------------
// grid = (8 k, 8 js), 512 threads (i). 64-deep reduction -> latency-cheap.
__global__ __launch_bounds__(512) void prompt_pre_kernel(
    const float* __restrict__ prompt, const float* __restrict__ w2,
    const float* __restrict__ b2, float* __restrict__ pp,
    float* __restrict__ pbp) {
  const int k = blockIdx.x, js = blockIdx.y;
  const int i = threadIdx.x;
  __shared__ float sP[64];
  if (i < 64) sP[i] = prompt[k * 512 + js * 64 + i];
  __syncthreads();
  float acc = 0.0f;
  const float* wcol = w2 + (js * 64) * 512 + i;   // coalesced over i
  #pragma unroll 8
  for (int jj = 0; jj < 64; ++jj) acc = fmaf(sP[jj], wcol[jj * 512], acc);
  pp[(k * 8 + js) * 512 + i] = acc;
  if (i < 64) {                                   // pb partial via wave-0 reduce
    float v = sP[i] * b2[js * 64 + i];
    #pragma unroll
    for (int m = 32; m > 0; m >>= 1) v += __shfl_xor(v, m);
    if (i == 0) pbp[k * 8 + js] = v;
  }
}

// ---------------- Kernel 1: pooling partials + NCHW->NHWC bf16 ---------------
// grid = B*H = 2048 blocks, 256 threads. Each block handles one (b,h) row slab.
__global__ __launch_bounds__(256) void pool_convert_kernel(
    const float* __restrict__ x, float* __restrict__ partial,
    __hip_bfloat16* __restrict__ xT) {
  const int b = blockIdx.x >> 6;
  const int h = blockIdx.x & 63;
  const int tid = threadIdx.x;
  const int wv = tid >> 6, lane = tid & 63;
  const int wq = lane & 15;                    // w-quad (4 w's) within row
  const int cl = lane >> 4;                    // channel within group-of-4
  // [w][c] transpose buffer; pitch 130 elems (260B) => 2-way bank aliasing (free)
  __shared__ __align__(16) __hip_bfloat16 sT[64 * 130];

  const float* xrow = x + (((size_t)b * 128) << 12) + (h << 6);
  #pragma unroll
  for (int i = 0; i < 8; ++i) {
    int c = wv * 32 + i * 4 + cl;              // each wave: 32 channels
    float4 v = *(const float4*)&xrow[((size_t)c << 12) + wq * 4];
    int w0 = wq * 4;
    sT[(w0 + 0) * 130 + c] = __float2bfloat16(v.x);
    sT[(w0 + 1) * 130 + c] = __float2bfloat16(v.y);
    sT[(w0 + 2) * 130 + c] = __float2bfloat16(v.z);
    sT[(w0 + 3) * 130 + c] = __float2bfloat16(v.w);
    float s = v.x + v.y + v.z + v.w;
    s += __shfl_xor(s, 1);
    s += __shfl_xor(s, 2);
    s += __shfl_xor(s, 4);
    s += __shfl_xor(s, 8);                     // sum over the 16-lane group
    if (wq == 0) partial[((b << 6) + h) * 128 + c] = s;  // unique slot
  }
  __syncthreads();
  // write NHWC: position (h,pw) has 256B of ci; 4 threads/position, 64B each
  const int pw = tid >> 2;
  const int piece = tid & 3;
  const uint32_t* s32 = (const uint32_t*)sT;
  uint32_t vals[16];
  #pragma unroll
  for (int j = 0; j < 16; ++j) vals[j] = s32[pw * 65 + piece * 16 + j];
  char* dst = (char*)xT + ((((size_t)b << 6) + h) * 64 + pw) * 256 + piece * 64;
  #pragma unroll
  for (int j = 0; j < 4; ++j)
    ((uint4*)dst)[j] = make_uint4(vals[4*j], vals[4*j+1], vals[4*j+2], vals[4*j+3]);
}

// ---------------- Kernel 2: fused attention ----------------------------------
// grid = 32 (b), 256 threads.
__global__ __launch_bounds__(256) void attn_fused_kernel(
    const float* __restrict__ partial, const float* __restrict__ w1,
    const float* __restrict__ b1, const float* __restrict__ pp,
    const float* __restrict__ pbp, const float* __restrict__ kbias,
    float* __restrict__ alphas, float* __restrict__ aggb) {
  const int b = blockIdx.x, tid = threadIdx.x;
  __shared__ float sTmp[256];
  __shared__ float sPool[128];
  __shared__ float sH[512];
  __shared__ float sS[8], sA[8];

  {  // 1) reduce partial[b][64][128] -> pooled. c = tid&127 (coalesced), 2 h-lanes
    const int c = tid & 127, hh = tid >> 7;
    const float* src = partial + ((size_t)b << 6) * 128 + hh * 128 + c;
    float acc = 0.0f;
    #pragma unroll
    for (int h2 = 0; h2 < 32; ++h2) acc += src[h2 * 256];
    sTmp[tid] = acc;
  }
  __syncthreads();
  if (tid < 128) sPool[tid] = (sTmp[tid] + sTmp[tid + 128]) * (1.0f / 4096.0f);
  __syncthreads();

  // 2) h = relu(pooled @ w1^T + b1): each thread 2 rows of w1 (L2-shared)
  #pragma unroll
  for (int q = 0; q < 2; ++q) {
    const int j = q * 256 + tid;
    const float* wr = w1 + j * 128;
    float acc = 0.0f;
    #pragma unroll
    for (int i4 = 0; i4 < 32; ++i4) {
      float4 wv = *(const float4*)&wr[i4 * 4];
      acc += wv.x * sPool[i4*4] + wv.y * sPool[i4*4+1] +
             wv.z * sPool[i4*4+2] + wv.w * sPool[i4*4+3];
    }
    sH[j] = fmaxf(acc + b1[j], 0.0f);
  }
  __syncthreads();

  {  // 3) scores[k] = sum_js pp_part[k][js]·h + sum_js pbp[k][js]
    const int k = tid >> 5, seg = tid & 31;
    const float* hk = sH + seg * 16;
    float acc = 0.0f;
    #pragma unroll
    for (int js = 0; js < 8; ++js) {
      const float* ppk = pp + (k * 8 + js) * 512 + seg * 16;
      #pragma unroll
      for (int t4 = 0; t4 < 4; ++t4) {
        float4 pv = *(const float4*)&ppk[t4 * 4];
        acc += pv.x * hk[t4*4] + pv.y * hk[t4*4+1] +
               pv.z * hk[t4*4+2] + pv.w * hk[t4*4+3];
      }
    }
    #pragma unroll
    for (int m = 16; m > 0; m >>= 1) acc += __shfl_xor(acc, m);
    if (seg == 0) {
      float pbk = 0.0f;
      #pragma unroll
      for (int js = 0; js < 8; ++js) pbk += pbp[k * 8 + js];
      sS[k] = acc + pbk;
    }
  }
  __syncthreads();

  // 4) softmax + outputs
  if (tid == 0) {
    float mx = sS[0];
    for (int k = 1; k < 8; ++k) mx = fmaxf(mx, sS[k]);
    float sum = 0.0f, e[8];
    for (int k = 0; k < 8; ++k) { e[k] = expf(sS[k] - mx); sum += e[k]; }
    float inv = 1.0f / sum;
    for (int k = 0; k < 8; ++k) sA[k] = e[k] * inv;
  }
  __syncthreads();
  if (tid < 8) alphas[b * 8 + tid] = sA[tid];
  if (tid < 128) {
    float acc = 0.0f;
    #pragma unroll
    for (int k = 0; k < 8; ++k) acc = fmaf(sA[k], kbias[k * 128 + tid], acc);
    aggb[b * 128 + tid] = acc;
  }
}

// ---------------- Kernel 3: aggregate conv weights -> bf16 -------------------
// grid = (co=128, bgroup=4), 128 threads.
__global__ __launch_bounds__(128) void agg_weights_kernel(
    const float* __restrict__ kw, const float* __restrict__ alphas,
    __hip_bfloat16* __restrict__ aggw) {
  const int co = blockIdx.x;
  const int bg = blockIdx.y;
  const int tid = threadIdx.x;
  __shared__ float sA[64];                          // [bb][k]
  __shared__ float sbuf[1152];
  if (tid < 64) sA[tid] = alphas[bg * 64 + tid];
  __syncthreads();

  float acc[8][9];                                  // [bb][q], f = tid + 128*q
  #pragma unroll
  for (int bb = 0; bb < 8; ++bb)
    #pragma unroll
    for (int q = 0; q < 9; ++q) acc[bb][q] = 0.0f;

  for (int k = 0; k < 8; ++k) {
    const float* src = kw + ((size_t)(k * 128 + co)) * 1152;
    float v[9];
    #pragma unroll
    for (int q = 0; q < 9; ++q) v[q] = src[tid + 128 * q];   // coalesced
    #pragma unroll
    for (int bb = 0; bb < 8; ++bb) {
      float a = sA[bb * 8 + k];
      #pragma unroll
      for (int q = 0; q < 9; ++q) acc[bb][q] = fmaf(a, v[q], acc[bb][q]);
    }
  }

  #pragma unroll 1
  for (int bb = 0; bb < 8; ++bb) {
    __syncthreads();
    #pragma unroll
    for (int q = 0; q < 9; ++q) sbuf[tid + 128 * q] = acc[bb][q];
    __syncthreads();
    const int b = bg * 8 + bb;
    // sbuf[f] with f = ci*9 + t; lanes read stride 9 (9 coprime 32: conflict-free)
    #pragma unroll
    for (int t = 0; t < 9; ++t)
      aggw[(((size_t)(b * 9 + t) * 128 + co) << 7) + tid] =
          __float2bfloat16(sbuf[tid * 9 + t]);     // 256B contiguous store
  }
}

// ---------------- Kernel 4: per-sample conv as implicit GEMM -----------------
// Round-7. Block tile: M=128 (co) x N=128 (2 rows x 64 cols), acc[4][4]/wave.
// K-loop: 2 halves x 18 chunks (9 taps x 2 subs) of BK=32, 16x16x32 bf16 MFMA.
// x staged per ci-half in LDS NHWC with 16B XOR swizzle; A staged per
// SUB-CHUNK in 2x8KB dbuf (stage c+2 after barrier; R0-proven pattern).
// LDS = 50.7KB -> 3 blocks/CU at natural VGPR (~124 <= 170 = 512/3).
// Full unroll -> no runtime division. No forced launch_bounds occupancy
// (R6's (256,3) spilled); no XCD swizzle (removed for clean attribution).
#define XTILE_B 33792   // 264 positions * 128B (64 ci bf16)
#define ABUF_B  8192    // one sub-chunk: 128 co * 64B

__global__ __launch_bounds__(256) void dyn_conv_kernel(
    const __hip_bfloat16* __restrict__ xT, const __hip_bfloat16* __restrict__ aggw,
    const float* __restrict__ aggb, float* __restrict__ out) {
  const int tile = blockIdx.x;   // 0..31 -> rows [2*tile, 2*tile+1]
  const int b    = blockIdx.y;   // sample
  const int tid  = threadIdx.x;
  const int wv = tid >> 6, lane = tid & 63;
  const int wm = wv >> 1, wn = wv & 1;
  const int lm = lane & 15, quad = lane >> 4;
  const int r0 = tile * 2;

  __shared__ __align__(16) char smem[XTILE_B + 2 * ABUF_B + 512];
  char* xb = smem;
  char* abuf = smem + XTILE_B;
  float* sBias = (float*)(smem + XTILE_B + 2 * ABUF_B);

  if (tid < 128) sBias[tid] = aggb[b * 128 + tid];

  // zero-fill halo slots that staging never writes (pad cols / out-of-range rows)
  for (int pos = tid; pos < 264; pos += 256) {
    int tr = pos / 66, tc = pos - tr * 66;
    int h = r0 - 1 + tr, w = tc - 1;
    if ((unsigned)h >= 64u || (unsigned)w >= 64u) {
      int4* d = (int4*)(xb + pos * 128);
      #pragma unroll
      for (int i = 0; i < 8; ++i) d[i] = make_int4(0, 0, 0, 0);
    }
  }

  const char* xTb = (const char*)xT + ((size_t)b << 20);     // b*4096*256
  const char* awb = (const char*)aggw + (size_t)b * 294912;  // b*9*128*256

  auto stageX = [&](int half) {
    for (int i = wv; i < 33; i += 4) {          // 33 issues of 64x16B = 1KB
      int P = (i << 6) + lane;
      int pos = P >> 3, slot = P & 7;
      int tr = pos / 66, tc = pos - tr * 66;
      int h = r0 - 1 + tr, w = tc - 1;
      char* dst = xb + (i << 10);               // wave-uniform LDS base
      if ((unsigned)h < 64u && (unsigned)w < 64u) {
        int p = slot ^ (pos & 7);               // swizzled source piece
        const char* src = xTb + (((h << 6) + w) << 8) + (half << 7) + (p << 4);
        g2l16(src, dst);
      }
    }
  };

  // stage one sub-chunk (8KB) into buffer c&1: 2 g2l16 per wave, branch-free
  auto stageA = [&](int c, int half) {          // c = chunk 0..17 within half
    const int tap = c >> 1, sub = c & 1;
    const int cic = half * 2 + sub;             // ci chunk 0..3
    char* ab = abuf + (c & 1) * ABUF_B;
    const char* base = awb + (tap << 15) + (cic << 6);
    #pragma unroll
    for (int jj = 0; jj < 2; ++jj) {
      int j = wv * 2 + jj;
      int co = (j << 4) + (lane >> 2);
      int f = lane & 3;
      int p = f ^ ((co >> 1) & 3);              // swizzled source piece
      g2l16(base + (co << 8) + (p << 4), ab + (j << 10));
    }
  };

  int posb[4];
  #pragma unroll
  for (int ni = 0; ni < 4; ++ni) {
    int n = wn * 64 + ni * 16 + lm;
    posb[ni] = (n >> 6) * 66 + (n & 63);
  }
  const int fA = (quad ^ ((lm >> 1) & 3)) << 4;
  int aoff[4];
  #pragma unroll
  for (int mi = 0; mi < 4; ++mi) {
    int co = wm * 64 + mi * 16 + lm;
    aoff[mi] = (co << 6) + fA;
  }

  v4f acc[4][4];
  #pragma unroll
  for (int mi = 0; mi < 4; ++mi)
    #pragma unroll
    for (int ni = 0; ni < 4; ++ni) acc[mi][ni] = v4f{0.f, 0.f, 0.f, 0.f};

  auto computeChunk = [&](int c) {              // c compile-time under unroll
    const int tap = c >> 1, sub = c & 1;
    const int th = tap / 3, tw = tap - th * 3;
    const int tapAdd = th * 66 + tw;
    char* ab = abuf + (c & 1) * ABUF_B;
    v8bf af[4], bfr[4];
    #pragma unroll
    for (int mi = 0; mi < 4; ++mi) af[mi] = *(const v8bf*)(ab + aoff[mi]);
    const int piece = (sub << 2) | quad;        // ci piece within half
    #pragma unroll
    for (int ni = 0; ni < 4; ++ni) {
      int pos = posb[ni] + tapAdd;
      int pq = (piece ^ (pos & 7)) << 4;
      bfr[ni] = *(const v8bf*)(xb + (pos << 7) + pq);
    }
    #pragma unroll
    for (int mi = 0; mi < 4; ++mi)
      #pragma unroll
      for (int ni = 0; ni < 4; ++ni)
        acc[mi][ni] = __builtin_amdgcn_mfma_f32_16x16x32_bf16(
            af[mi], bfr[ni], acc[mi][ni], 0, 0, 0);
  };

  // ---- half 0 ----
  stageA(0, 0);
  stageA(1, 0);
  stageX(0);
  __syncthreads();                              // drains all staging
  #pragma unroll
  for (int c = 0; c < 18; ++c) {
    computeChunk(c);
    __syncthreads();                            // all waves done with buf c&1
    if (c + 2 < 18) stageA(c + 2, 0);           // lands during computeChunk(c+1)
  }
  // ---- half transition (all buffers free after chunk-17 barrier) ----
  stageX(1);
  stageA(0, 1);
  stageA(1, 1);
  __syncthreads();
  // ---- half 1 ----
  #pragma unroll
  for (int c = 0; c < 18; ++c) {
    computeChunk(c);
    if (c < 17) {
      __syncthreads();
      if (c + 2 < 18) stageA(c + 2, 1);
    }
  }

  // ---- epilogue: C/D layout col=lane&15, row=quad*4+reg ----
  #pragma unroll
  for (int mi = 0; mi < 4; ++mi) {
    #pragma unroll
    for (int r = 0; r < 4; ++r) {
      int co = wm * 64 + mi * 16 + quad * 4 + r;
      float bias = sBias[co];
      #pragma unroll
      for (int ni = 0; ni < 4; ++ni) {
        int n = wn * 64 + ni * 16 + lm;
        out[(((size_t)(b * 128 + co)) << 12) + tile * 128 + n] =
            acc[mi][ni][r] + bias;
      }
    }
  }
}

// ---------------------------------- launch -----------------------------------
extern "C" void kernel_launch(void* const* d_in, const int* in_sizes, int n_in,
                              void* d_out, int out_size, void* d_ws, size_t ws_size,
                              hipStream_t stream) {
  const float* x      = (const float*)d_in[0];
  const float* prompt = (const float*)d_in[1];
  const float* w1     = (const float*)d_in[2];
  const float* b1     = (const float*)d_in[3];
  const float* w2     = (const float*)d_in[4];
  const float* b2     = (const float*)d_in[5];
  const float* kw     = (const float*)d_in[6];
  const float* kb     = (const float*)d_in[7];
  float* out = (float*)d_out;
  char* ws = (char*)d_ws;

  __hip_bfloat16* xT   = (__hip_bfloat16*)(ws + XT_OFF);
  __hip_bfloat16* aggw = (__hip_bfloat16*)(ws + AGGW_OFF);
  float* part   = (float*)(ws + PART_OFF);     // aliases AGGW (dead before agg)
  float* pp     = (float*)(ws + PP_OFF);       // "
  float* pbp    = (float*)(ws + PBP_OFF);      // "
  float* alphas = (float*)(ws + ALPHA_OFF);
  float* aggb   = (float*)(ws + AGGB_OFF);

  prompt_pre_kernel<<<dim3(8, 8), 512, 0, stream>>>(prompt, w2, b2, pp, pbp);
  pool_convert_kernel<<<2048, 256, 0, stream>>>(x, part, xT);
  attn_fused_kernel<<<32, 256, 0, stream>>>(part, w1, b1, pp, pbp, kb,
                                            alphas, aggb);
  agg_weights_kernel<<<dim3(128, 4), 128, 0, stream>>>(kw, alphas, aggw);
  dyn_conv_kernel<<<dim3(32, 32), 256, 0, stream>>>(xT, aggw, aggb, out);
}

// Round 8
// 208.382 us; speedup vs baseline: 1.1806x; 1.0288x over previous
//
#include <hip/hip_runtime.h>
#include <hip/hip_bf16.h>
#include <stdint.h>

// Problem: B=32, C_IN=128, H=W=64, K=8, C_OUT=128, KS=3, HID=512, pad=1
// Pipeline (Round-8):
//  0) prompt_pre:   pp_part[k][js] = prompt[k] @ w2[js-chunk] (j-split x8)
//  1) pool_convert: x fp32 NCHW -> per-(b,h) partial sums + xT bf16 NHWC
//  2) attn_fused:   partial -> pooled -> h -> scores(pp_part) -> softmax
//  3) agg_weights:  alphas x kernels_weights -> aggw bf16 [b][tap][co][ci]
//  4) dyn_conv:     R3-EXACT structure (tap-batched A staging 2x16KB, 19
//     barriers, full unroll -- proven 47.4us; R4 counted-vmcnt null, R7
//     3-block/37-barrier null => this is the schedule optimum) plus ONE
//     delta: bijective XCD tile swizzle so the 4 tiles sharing halo rows
//     land on the SAME XCD's L2 (FETCH showed zero halo reuse: 69.3MB =
//     1024 x 67.6KB exactly).

typedef __bf16 v8bf __attribute__((ext_vector_type(8)));
typedef float  v4f  __attribute__((ext_vector_type(4)));

// ---- workspace layout (bytes) ----
#define XT_OFF     0u
#define XT_BYTES   (32u*4096u*128u*2u)        // 33,554,432  x as bf16 NHWC
#define AGGW_OFF   (XT_OFF + XT_BYTES)
#define AGGW_BYTES (32u*9u*128u*128u*2u)      // 9,437,184   [b][tap][co][ci]
// scratch below ALIASES the AGGW region: all consumed before agg_weights writes
#define PART_OFF   (AGGW_OFF)                 // 32*64*128 fp32 = 1 MB
#define PP_OFF     (AGGW_OFF + 0x100000u)     // 8*8*512 fp32 = 128 KB
#define PBP_OFF    (AGGW_OFF + 0x120000u)     // 64 fp32
#define ALPHA_OFF  (AGGW_OFF + AGGW_BYTES)
#define ALPHA_BYTES (32u*8u*4u)
#define AGGB_OFF   (ALPHA_OFF + ALPHA_BYTES)
#define AGGB_BYTES (32u*128u*4u)

typedef const void __attribute__((address_space(1))) gconst_t;
typedef void       __attribute__((address_space(3))) ldsv_t;

__device__ __forceinline__ void g2l16(const void* g, void* l) {
  // async global->LDS, 16B/lane; LDS dest is wave-uniform base (HW adds lane*16)
  __builtin_amdgcn_global_load_lds((gconst_t*)g, (ldsv_t*)l, 16, 0, 0);
}

// ---------------- Kernel 0: prompt premix, j-split x8 ------------------------
// grid = (8 k, 8 js), 512 threads (i). 64-deep reduction -> latency-cheap.
__global__ __launch_bounds__(512) void prompt_pre_kernel(
    const float* __restrict__ prompt, const float* __restrict__ w2,
    const float* __restrict__ b2, float* __restrict__ pp,
    float* __restrict__ pbp) {
  const int k = blockIdx.x, js = blockIdx.y;
  const int i = threadIdx.x;
  __shared__ float sP[64];
  if (i < 64) sP[i] = prompt[k * 512 + js * 64 + i];
  __syncthreads();
  float acc = 0.0f;
  const float* wcol = w2 + (js * 64) * 512 + i;   // coalesced over i
  #pragma unroll 8
  for (int jj = 0; jj < 64; ++jj) acc = fmaf(sP[jj], wcol[jj * 512], acc);
  pp[(k * 8 + js) * 512 + i] = acc;
  if (i < 64) {                                   // pb partial via wave-0 reduce
    float v = sP[i] * b2[js * 64 + i];
    #pragma unroll
    for (int m = 32; m > 0; m >>= 1) v += __shfl_xor(v, m);
    if (i == 0) pbp[k * 8 + js] = v;
  }
}

// ---------------- Kernel 1: pooling partials + NCHW->NHWC bf16 ---------------
// grid = B*H = 2048 blocks, 256 threads. Each block handles one (b,h) row slab.
__global__ __launch_bounds__(256) void pool_convert_kernel(
    const float* __restrict__ x, float* __restrict__ partial,
    __hip_bfloat16* __restrict__ xT) {
  const int b = blockIdx.x >> 6;
  const int h = blockIdx.x & 63;
  const int tid = threadIdx.x;
  const int wv = tid >> 6, lane = tid & 63;
  const int wq = lane & 15;                    // w-quad (4 w's) within row
  const int cl = lane >> 4;                    // channel within group-of-4
  // [w][c] transpose buffer; pitch 130 elems (260B) => 2-way bank aliasing (free)
  __shared__ __align__(16) __hip_bfloat16 sT[64 * 130];

  const float* xrow = x + (((size_t)b * 128) << 12) + (h << 6);
  #pragma unroll
  for (int i = 0; i < 8; ++i) {
    int c = wv * 32 + i * 4 + cl;              // each wave: 32 channels
    float4 v = *(const float4*)&xrow[((size_t)c << 12) + wq * 4];
    int w0 = wq * 4;
    sT[(w0 + 0) * 130 + c] = __float2bfloat16(v.x);
    sT[(w0 + 1) * 130 + c] = __float2bfloat16(v.y);
    sT[(w0 + 2) * 130 + c] = __float2bfloat16(v.z);
    sT[(w0 + 3) * 130 + c] = __float2bfloat16(v.w);
    float s = v.x + v.y + v.z + v.w;
    s += __shfl_xor(s, 1);
    s += __shfl_xor(s, 2);
    s += __shfl_xor(s, 4);
    s += __shfl_xor(s, 8);                     // sum over the 16-lane group
    if (wq == 0) partial[((b << 6) + h) * 128 + c] = s;  // unique slot
  }
  __syncthreads();
  // write NHWC: position (h,pw) has 256B of ci; 4 threads/position, 64B each
  const int pw = tid >> 2;
  const int piece = tid & 3;
  const uint32_t* s32 = (const uint32_t*)sT;
  uint32_t vals[16];
  #pragma unroll
  for (int j = 0; j < 16; ++j) vals[j] = s32[pw * 65 + piece * 16 + j];
  char* dst = (char*)xT + ((((size_t)b << 6) + h) * 64 + pw) * 256 + piece * 64;
  #pragma unroll
  for (int j = 0; j < 4; ++j)
    ((uint4*)dst)[j] = make_uint4(vals[4*j], vals[4*j+1], vals[4*j+2], vals[4*j+3]);
}

// ---------------- Kernel 2: fused attention ----------------------------------
// grid = 32 (b), 256 threads.
__global__ __launch_bounds__(256) void attn_fused_kernel(
    const float* __restrict__ partial, const float* __restrict__ w1,
    const float* __restrict__ b1, const float* __restrict__ pp,
    const float* __restrict__ pbp, const float* __restrict__ kbias,
    float* __restrict__ alphas, float* __restrict__ aggb) {
  const int b = blockIdx.x, tid = threadIdx.x;
  __shared__ float sTmp[256];
  __shared__ float sPool[128];
  __shared__ float sH[512];
  __shared__ float sS[8], sA[8];

  {  // 1) reduce partial[b][64][128] -> pooled. c = tid&127 (coalesced), 2 h-lanes
    const int c = tid & 127, hh = tid >> 7;
    const float* src = partial + ((size_t)b << 6) * 128 + hh * 128 + c;
    float acc = 0.0f;
    #pragma unroll
    for (int h2 = 0; h2 < 32; ++h2) acc += src[h2 * 256];
    sTmp[tid] = acc;
  }
  __syncthreads();
  if (tid < 128) sPool[tid] = (sTmp[tid] + sTmp[tid + 128]) * (1.0f / 4096.0f);
  __syncthreads();

  // 2) h = relu(pooled @ w1^T + b1): each thread 2 rows of w1 (L2-shared)
  #pragma unroll
  for (int q = 0; q < 2; ++q) {
    const int j = q * 256 + tid;
    const float* wr = w1 + j * 128;
    float acc = 0.0f;
    #pragma unroll
    for (int i4 = 0; i4 < 32; ++i4) {
      float4 wv = *(const float4*)&wr[i4 * 4];
      acc += wv.x * sPool[i4*4] + wv.y * sPool[i4*4+1] +
             wv.z * sPool[i4*4+2] + wv.w * sPool[i4*4+3];
    }
    sH[j] = fmaxf(acc + b1[j], 0.0f);
  }
  __syncthreads();

  {  // 3) scores[k] = sum_js pp_part[k][js]·h + sum_js pbp[k][js]
    const int k = tid >> 5, seg = tid & 31;
    const float* hk = sH + seg * 16;
    float acc = 0.0f;
    #pragma unroll
    for (int js = 0; js < 8; ++js) {
      const float* ppk = pp + (k * 8 + js) * 512 + seg * 16;
      #pragma unroll
      for (int t4 = 0; t4 < 4; ++t4) {
        float4 pv = *(const float4*)&ppk[t4 * 4];
        acc += pv.x * hk[t4*4] + pv.y * hk[t4*4+1] +
               pv.z * hk[t4*4+2] + pv.w * hk[t4*4+3];
      }
    }
    #pragma unroll
    for (int m = 16; m > 0; m >>= 1) acc += __shfl_xor(acc, m);
    if (seg == 0) {
      float pbk = 0.0f;
      #pragma unroll
      for (int js = 0; js < 8; ++js) pbk += pbp[k * 8 + js];
      sS[k] = acc + pbk;
    }
  }
  __syncthreads();

  // 4) softmax + outputs
  if (tid == 0) {
    float mx = sS[0];
    for (int k = 1; k < 8; ++k) mx = fmaxf(mx, sS[k]);
    float sum = 0.0f, e[8];
    for (int k = 0; k < 8; ++k) { e[k] = expf(sS[k] - mx); sum += e[k]; }
    float inv = 1.0f / sum;
    for (int k = 0; k < 8; ++k) sA[k] = e[k] * inv;
  }
  __syncthreads();
  if (tid < 8) alphas[b * 8 + tid] = sA[tid];
  if (tid < 128) {
    float acc = 0.0f;
    #pragma unroll
    for (int k = 0; k < 8; ++k) acc = fmaf(sA[k], kbias[k * 128 + tid], acc);
    aggb[b * 128 + tid] = acc;
  }
}

// ---------------- Kernel 3: aggregate conv weights -> bf16 -------------------
// grid = (co=128, bgroup=4), 128 threads.
__global__ __launch_bounds__(128) void agg_weights_kernel(
    const float* __restrict__ kw, const float* __restrict__ alphas,
    __hip_bfloat16* __restrict__ aggw) {
  const int co = blockIdx.x;
  const int bg = blockIdx.y;
  const int tid = threadIdx.x;
  __shared__ float sA[64];                          // [bb][k]
  __shared__ float sbuf[1152];
  if (tid < 64) sA[tid] = alphas[bg * 64 + tid];
  __syncthreads();

  float acc[8][9];                                  // [bb][q], f = tid + 128*q
  #pragma unroll
  for (int bb = 0; bb < 8; ++bb)
    #pragma unroll
    for (int q = 0; q < 9; ++q) acc[bb][q] = 0.0f;

  for (int k = 0; k < 8; ++k) {
    const float* src = kw + ((size_t)(k * 128 + co)) * 1152;
    float v[9];
    #pragma unroll
    for (int q = 0; q < 9; ++q) v[q] = src[tid + 128 * q];   // coalesced
    #pragma unroll
    for (int bb = 0; bb < 8; ++bb) {
      float a = sA[bb * 8 + k];
      #pragma unroll
      for (int q = 0; q < 9; ++q) acc[bb][q] = fmaf(a, v[q], acc[bb][q]);
    }
  }

  #pragma unroll 1
  for (int bb = 0; bb < 8; ++bb) {
    __syncthreads();
    #pragma unroll
    for (int q = 0; q < 9; ++q) sbuf[tid + 128 * q] = acc[bb][q];
    __syncthreads();
    const int b = bg * 8 + bb;
    // sbuf[f] with f = ci*9 + t; lanes read stride 9 (9 coprime 32: conflict-free)
    #pragma unroll
    for (int t = 0; t < 9; ++t)
      aggw[(((size_t)(b * 9 + t) * 128 + co) << 7) + tid] =
          __float2bfloat16(sbuf[tid * 9 + t]);     // 256B contiguous store
  }
}

// ---------------- Kernel 4: per-sample conv as implicit GEMM -----------------
// Round-8 = Round-3 EXACT (proven 47.4us) + XCD tile swizzle.
// Block tile: M=128 (co) x N=128 (2 rows x 64 cols), acc[4][4]/wave.
// K-loop: 9 taps x 2 ci-halves; per tap 2 chunks of BK=32, 16x16x32 bf16 MFMA.
// x staged per ci-half in LDS NHWC with 16B XOR swizzle; A staged in 2x16KB
// tap-buffers; barrier per TAP (19 total); stage(tap+2) after the barrier.
// XCD swizzle: XCD = linear_id%8 = blockIdx.x%8 (gridDim.x=32, x fastest);
// tile=((x&7)<<2)|(x>>3) gives XCD k tiles {4k..4k+3} -> halo rows L2-shared.
#define XTILE_B 33792   // 264 positions * 128B (64 ci bf16)
#define ABUF_B  16384   // one tap: 2 subs x 128 co x 64B

__global__ __launch_bounds__(256) void dyn_conv_kernel(
    const __hip_bfloat16* __restrict__ xT, const __hip_bfloat16* __restrict__ aggw,
    const float* __restrict__ aggb, float* __restrict__ out) {
  const int tile = ((blockIdx.x & 7) << 2) | (blockIdx.x >> 3);  // bijective
  const int b    = blockIdx.y;   // sample
  const int tid  = threadIdx.x;
  const int wv = tid >> 6, lane = tid & 63;
  const int wm = wv >> 1, wn = wv & 1;
  const int lm = lane & 15, quad = lane >> 4;
  const int r0 = tile * 2;

  __shared__ __align__(16) char smem[XTILE_B + 2 * ABUF_B + 512];
  char* xb = smem;
  char* abuf = smem + XTILE_B;
  float* sBias = (float*)(smem + XTILE_B + 2 * ABUF_B);

  if (tid < 128) sBias[tid] = aggb[b * 128 + tid];

  // zero-fill halo slots that staging never writes (pad cols / out-of-range rows)
  for (int pos = tid; pos < 264; pos += 256) {
    int tr = pos / 66, tc = pos - tr * 66;
    int h = r0 - 1 + tr, w = tc - 1;
    if ((unsigned)h >= 64u || (unsigned)w >= 64u) {
      int4* d = (int4*)(xb + pos * 128);
      #pragma unroll
      for (int i = 0; i < 8; ++i) d[i] = make_int4(0, 0, 0, 0);
    }
  }

  const char* xTb = (const char*)xT + ((size_t)b << 20);     // b*4096*256
  const char* awb = (const char*)aggw + (size_t)b * 294912;  // b*9*128*256

  auto stageX = [&](int half) {
    for (int i = wv; i < 33; i += 4) {          // 33 issues of 64x16B = 1KB
      int P = (i << 6) + lane;
      int pos = P >> 3, slot = P & 7;
      int tr = pos / 66, tc = pos - tr * 66;
      int h = r0 - 1 + tr, w = tc - 1;
      char* dst = xb + (i << 10);               // wave-uniform LDS base
      if ((unsigned)h < 64u && (unsigned)w < 64u) {
        int p = slot ^ (pos & 7);               // swizzled source piece
        const char* src = xTb + (((h << 6) + w) << 8) + (half << 7) + (p << 4);
        g2l16(src, dst);
      }
    }
  };

  // stage one tap (2 chunks) into buffer tap&1
  auto stageA = [&](int tap, int half) {
    char* ab = abuf + (tap & 1) * ABUF_B;
    #pragma unroll
    for (int sub = 0; sub < 2; ++sub) {
      const int cic = half * 2 + sub;           // ci chunk 0..3
      const char* base = awb + (tap << 15) + (cic << 6);
      #pragma unroll
      for (int jj = 0; jj < 2; ++jj) {
        int j = wv * 2 + jj;
        int co = (j << 4) + (lane >> 2);
        int f = lane & 3;
        int p = f ^ ((co >> 1) & 3);            // swizzled source piece
        g2l16(base + (co << 8) + (p << 4), ab + sub * 8192 + (j << 10));
      }
    }
  };

  int posb[4];
  #pragma unroll
  for (int ni = 0; ni < 4; ++ni) {
    int n = wn * 64 + ni * 16 + lm;
    posb[ni] = (n >> 6) * 66 + (n & 63);
  }
  const int fA = (quad ^ ((lm >> 1) & 3)) << 4;
  int aoff[4];
  #pragma unroll
  for (int mi = 0; mi < 4; ++mi) {
    int co = wm * 64 + mi * 16 + lm;
    aoff[mi] = (co << 6) + fA;
  }

  v4f acc[4][4];
  #pragma unroll
  for (int mi = 0; mi < 4; ++mi)
    #pragma unroll
    for (int ni = 0; ni < 4; ++ni) acc[mi][ni] = v4f{0.f, 0.f, 0.f, 0.f};

  auto computeTap = [&](int tap) {              // tap is compile-time constant
    const int th = tap / 3, tw = tap - th * 3;
    const int tapAdd = th * 66 + tw;
    char* ab = abuf + (tap & 1) * ABUF_B;
    #pragma unroll
    for (int sub = 0; sub < 2; ++sub) {
      v8bf af[4], bfr[4];
      #pragma unroll
      for (int mi = 0; mi < 4; ++mi)
        af[mi] = *(const v8bf*)(ab + sub * 8192 + aoff[mi]);
      const int piece = (sub << 2) | quad;      // ci piece within half
      #pragma unroll
      for (int ni = 0; ni < 4; ++ni) {
        int pos = posb[ni] + tapAdd;
        int pp = (piece ^ (pos & 7)) << 4;
        bfr[ni] = *(const v8bf*)(xb + (pos << 7) + pp);
      }
      #pragma unroll
      for (int mi = 0; mi < 4; ++mi)
        #pragma unroll
        for (int ni = 0; ni < 4; ++ni)
          acc[mi][ni] = __builtin_amdgcn_mfma_f32_16x16x32_bf16(
              af[mi], bfr[ni], acc[mi][ni], 0, 0, 0);
    }
  };

  // ---- half 0 ----
  stageA(0, 0);
  stageA(1, 0);
  stageX(0);
  __syncthreads();                              // drains all staging
  #pragma unroll
  for (int tap = 0; tap < 9; ++tap) {
    computeTap(tap);
    __syncthreads();                            // all waves done with buf tap&1
    if (tap + 2 < 9) stageA(tap + 2, 0);        // overlaps computeTap(tap+1)
  }
  // ---- half transition (buffers all free after tap-8 barrier) ----
  stageX(1);
  stageA(0, 1);
  stageA(1, 1);
  __syncthreads();
  // ---- half 1 ----
  #pragma unroll
  for (int tap = 0; tap < 9; ++tap) {
    computeTap(tap);
    if (tap < 8) {
      __syncthreads();
      if (tap + 2 < 9) stageA(tap + 2, 1);
    }
  }

  // ---- epilogue: C/D layout col=lane&15, row=quad*4+reg ----
  #pragma unroll
  for (int mi = 0; mi < 4; ++mi) {
    #pragma unroll
    for (int r = 0; r < 4; ++r) {
      int co = wm * 64 + mi * 16 + quad * 4 + r;
      float bias = sBias[co];
      #pragma unroll
      for (int ni = 0; ni < 4; ++ni) {
        int n = wn * 64 + ni * 16 + lm;
        out[(((size_t)(b * 128 + co)) << 12) + tile * 128 + n] =
            acc[mi][ni][r] + bias;
      }
    }
  }
}

// ---------------------------------- launch -----------------------------------
extern "C" void kernel_launch(void* const* d_in, const int* in_sizes, int n_in,
                              void* d_out, int out_size, void* d_ws, size_t ws_size,
                              hipStream_t stream) {
  const float* x      = (const float*)d_in[0];
  const float* prompt = (const float*)d_in[1];
  const float* w1     = (const float*)d_in[2];
  const float* b1     = (const float*)d_in[3];
  const float* w2     = (const float*)d_in[4];
  const float* b2     = (const float*)d_in[5];
  const float* kw     = (const float*)d_in[6];
  const float* kb     = (const float*)d_in[7];
  float* out = (float*)d_out;
  char* ws = (char*)d_ws;

  __hip_bfloat16* xT   = (__hip_bfloat16*)(ws + XT_OFF);
  __hip_bfloat16* aggw = (__hip_bfloat16*)(ws + AGGW_OFF);
  float* part   = (float*)(ws + PART_OFF);     // aliases AGGW (dead before agg)
  float* pp     = (float*)(ws + PP_OFF);       // "
  float* pbp    = (float*)(ws + PBP_OFF);      // "
  float* alphas = (float*)(ws + ALPHA_OFF);
  float* aggb   = (float*)(ws + AGGB_OFF);

  prompt_pre_kernel<<<dim3(8, 8), 512, 0, stream>>>(prompt, w2, b2, pp, pbp);
  pool_convert_kernel<<<2048, 256, 0, stream>>>(x, part, xT);
  attn_fused_kernel<<<32, 256, 0, stream>>>(part, w1, b1, pp, pbp, kb,
                                            alphas, aggb);
  agg_weights_kernel<<<dim3(128, 4), 128, 0, stream>>>(kw, alphas, aggw);
  dyn_conv_kernel<<<dim3(32, 32), 256, 0, stream>>>(xT, aggw, aggb, out);
}